// Round 4
// baseline (197.509 us; speedup 1.0000x reference)
//
#include <hip/hip_runtime.h>
#include <cstdint>

typedef unsigned long long u64;

#define RFL(x) __builtin_amdgcn_readfirstlane(x)

// Dims: B=2, S=1024, C=512, H=8, hd=64, T=4.
// bits layout: [3(qkv)][4(t)][2(b)][8(h)][1024(s)] u64 (bit d = channel h*64+d)
// vt   layout: [2(b)][8(h)][4(t)][16(w)][64(d)]  u64 (bit j = k-index w*64+j)
// ws usage: bits 1.5 MiB + vt 0.5 MiB = 2.0 MiB.

// ---------------- Kernel A3: y = x@W^T (one of q/k/v per block), LIF, pack.
// lane = output channel within head; 16 rows/wave, 64 rows/block, grid 32x8x3.
// W chunk staged in LDS [64ch][36] (pad+4): ds_write_b128 and ds_read_b128
// both hit bank-group starts 4*(ch+kq)%32 -> all 8 groups covered -> peak LDS
// BW, no conflicts. x loads are wave-uniform -> scalar (SMEM) loads.
// FMA order: ascending k, float4-paired -> bitwise-identical y to R0/R1/R2.
__global__ __launch_bounds__(256) void gemm_lif_pack3(
    const float* __restrict__ x,    // [2048][512]
    const float* __restrict__ Wq,
    const float* __restrict__ Wk,
    const float* __restrict__ Wv,
    u64* __restrict__ bits)
{
    __shared__ __align__(16) float wlds[64][36];   // 9.2 KiB

    const int tid  = threadIdx.x;
    const int lane = tid & 63;
    const int wave = RFL(tid >> 6);
    const int bx = blockIdx.x;          // 32 tiles of 64 rows
    const int by = blockIdx.y;          // head
    const int bz = blockIdx.z;          // 0=q 1=k 2=v
    const float* W = (bz == 0) ? Wq : (bz == 1) ? Wk : Wv;

    const int r0 = bx * 64 + wave * 16;             // 16 rows for this wave
    const float* __restrict__ xr   = x + (size_t)r0 * 512;
    const float* __restrict__ Wsrc = W + (size_t)(by * 64) * 512;

    float acc[16];
#pragma unroll
    for (int r = 0; r < 16; ++r) acc[r] = 0.f;

    for (int k0 = 0; k0 < 512; k0 += 32) {
        // ---- stage W chunk: 64ch x 32k = 512 float4, 2 per thread, coalesced
#pragma unroll
        for (int p = 0; p < 2; ++p) {
            const int fi = p * 256 + tid;   // 0..511
            const int ch = fi >> 3;         // 8 float4 per channel row
            const int kq = fi & 7;
            const float4 v4 = *(const float4*)(Wsrc + (size_t)ch * 512 + k0 + kq * 4);
            *(float4*)&wlds[ch][kq * 4] = v4;   // b128, conflict-free (pad 36)
        }
        __syncthreads();

        // ---- compute 32 k-steps: per g, 1 ds_read_b128 feeds 64 FMAs
#pragma unroll
        for (int g = 0; g < 8; ++g) {
            const float4 w4 = *(const float4*)&wlds[lane][g * 4];
#pragma unroll
            for (int r = 0; r < 16; ++r) {
                const float4 x4 = *(const float4*)(xr + (size_t)r * 512 + k0 + g * 4);
                acc[r] = fmaf(x4.x, w4.x, acc[r]);
                acc[r] = fmaf(x4.y, w4.y, acc[r]);
                acc[r] = fmaf(x4.z, w4.z, acc[r]);
                acc[r] = fmaf(x4.w, w4.w, acc[r]);
            }
        }
        __syncthreads();
    }

    // ---- LIF + ballot pack
#pragma unroll
    for (int r = 0; r < 16; ++r) {
        const float y = acc[r];
        float v = 0.f;
        int sp[4];
#pragma unroll
        for (int t = 0; t < 4; ++t) {
            v = v + (y - v) * 0.5f;           // decay_input charge, tau=2
            const int s = (v - 1.0f >= 0.f) ? 1 : 0;
            v = s ? 0.f : v;                  // hard reset
            sp[t] = s;
        }
        const int row = r0 + r;
        const int bb = row >> 10;
        const int ss = row & 1023;
        u64* dst = bits + (((size_t)(bz * 4) * 2 + bb) * 8 + by) * 1024 + ss;
#pragma unroll
        for (int t = 0; t < 4; ++t) {
            const u64 msk = __ballot(sp[t]);
            if (lane == 0) dst[(size_t)t * (2 * 8 * 1024)] = msk;
        }
    }
}

// ---------------- Kernel T2: bit-transpose of v spikes (w-split, coalesced store)
__global__ __launch_bounds__(256) void v_transpose2(
    const u64* __restrict__ bits,
    u64* __restrict__ vt)
{
    const int lane = threadIdx.x & 63;
    const int t  = threadIdx.x >> 6;      // one wave per timestep
    const int b  = blockIdx.x;
    const int h  = blockIdx.y;
    const int wg = blockIdx.z;            // 4 w's per block
    const u64* __restrict__ src = bits + (((size_t)(2 * 4 + t) * 2 + b) * 8 + h) * 1024;
    u64* __restrict__ dst = vt + (((size_t)b * 8 + h) * 4 + t) * 1024;
    for (int wi = 0; wi < 4; ++wi) {
        const int w = wg * 4 + wi;
        const u64 vword = src[(w << 6) + lane];
        u64 myword = 0;
#pragma unroll
        for (int d = 0; d < 64; ++d) {
            const u64 m = __ballot((int)((vword >> d) & 1ull));
            if (lane == d) myword = m;
        }
        dst[(w << 6) + lane] = myword;    // coalesced
    }
}

// ---------------- Kernel B3: exact q-row filter + integer LIF slow path.
// Score spike at (s,k,t) requires u>=64 with u <= 7.5*max_t pc_t (no-reset
// upper bound) and pc_t <= popcount(q_t[s]); so max_t popcount(q_t[s]) <= 8
// implies NO spike for row s against any k -> output = sum_t cs_t * 2^-12.
__global__ __launch_bounds__(256) void spike_attn3(
    const u64* __restrict__ bits,
    const u64* __restrict__ vt,
    float* __restrict__ out)
{
    const int lane = threadIdx.x & 63;
    const int wave = RFL((int)(threadIdx.x >> 6));
    const int rt = blockIdx.x;   // 32 tiles of 32 rows
    const int h  = blockIdx.y;
    const int b  = blockIdx.z;

    const int bh = b * 8 + h;
    const u64* __restrict__ qb  = bits + (size_t)bh * 1024;         // + t*16384 + s
    const u64* __restrict__ kb  = bits + (size_t)(64 + bh) * 1024;  // + t*16384 + k
    const u64* __restrict__ vtb = vt + (size_t)bh * 4096;           // + t*1024 + w*64 + d

    // column counts of v spikes (lane = d), per t
    int cs[4] = {0, 0, 0, 0};
    for (int w = 0; w < 16; ++w) {
#pragma unroll
        for (int t = 0; t < 4; ++t)
            cs[t] += (int)__popcll(vtb[t * 1024 + (w << 6) + lane]);
    }
    const float base = (float)(cs[0] + cs[1] + cs[2] + cs[3]) * (1.0f / 4096.0f);

    const float E1 = 0.36787944117144233f;  // expf(-1)
    const int s0 = rt * 32 + wave * 8;      // 8 rows per wave

    for (int r = 0; r < 8; ++r) {
        const int s = s0 + r;
        const u64 q0 = qb[s];
        const u64 q1 = qb[16384 + s];
        const u64 q2 = qb[32768 + s];
        const u64 q3 = qb[49152 + s];
        const int c0 = (int)__popcll(q0), c1 = (int)__popcll(q1);
        const int c2 = (int)__popcll(q2), c3 = (int)__popcll(q3);
        const int mx = max(max(c0, c1), max(c2, c3));

        float o = base;
        if (mx >= 9) {   // wave-uniform, essentially never taken; exact path
            int msum[4] = {0, 0, 0, 0}, n11[4] = {0, 0, 0, 0};
            for (int w = 0; w < 16; ++w) {
                const int ko = (w << 6) + lane;
                const u64 kw0 = kb[ko];
                const u64 kw1 = kb[16384 + ko];
                const u64 kw2 = kb[32768 + ko];
                const u64 kw3 = kb[49152 + ko];
                const int pcs[4] = {
                    (int)__popcll(kw0 & q0), (int)__popcll(kw1 & q1),
                    (int)__popcll(kw2 & q2), (int)__popcll(kw3 & q3)};
                unsigned u = 0;
#pragma unroll
                for (int t = 0; t < 4; ++t) {
                    u = (u >> 1) + (unsigned)(pcs[t] << 2);  // 64ths; exact
                    const int spk = (u >= 64u) ? 1 : 0;
                    const u64 msk = __ballot(spk);
                    u = spk ? 0u : u;
                    msum[t] += (int)__popcll(msk);
                    n11[t]  += (int)__popcll(msk & vtb[t * 1024 + ko]);
                }
            }
            o = 0.f;
#pragma unroll
            for (int t = 0; t < 4; ++t) {
                const float mf = (float)msum[t];
                const float Z  = mf + (1024.f - mf) * E1;
                const float p1 = 1.0f / Z;
                const float p0 = E1 / Z;                 // exactly 2^-10 when m==0
                o += p0 * (float)cs[t] + (p1 - p0) * (float)n11[t];
            }
            o *= 0.25f;
        }
        out[((size_t)b * 1024 + s) * 512 + (h << 6) + lane] = o;
    }
}

extern "C" void kernel_launch(void* const* d_in, const int* in_sizes, int n_in,
                              void* d_out, int out_size, void* d_ws, size_t ws_size,
                              hipStream_t stream) {
    const float* x  = (const float*)d_in[0];
    const float* Wq = (const float*)d_in[1];
    const float* Wk = (const float*)d_in[2];
    const float* Wv = (const float*)d_in[3];
    float* out = (float*)d_out;

    u64* bits = (u64*)d_ws;                          // 1.5 MiB
    u64* vt   = bits + (size_t)3 * 4 * 2 * 8 * 1024; // 0.5 MiB

    gemm_lif_pack3<<<dim3(32, 8, 3), 256, 0, stream>>>(x, Wq, Wk, Wv, bits);
    v_transpose2<<<dim3(2, 8, 4), 256, 0, stream>>>(bits, vt);
    spike_attn3<<<dim3(32, 8, 2), 256, 0, stream>>>(bits, vt, out);
}

// Round 5
// 77.835 us; speedup vs baseline: 2.5375x; 2.5375x over previous
//
#include <hip/hip_runtime.h>
#include <cstdint>

typedef unsigned long long u64;
typedef __attribute__((ext_vector_type(8))) short short8;   // 8 bf16 = 4 VGPR
typedef __attribute__((ext_vector_type(4))) float f32x4;

#define RFL(x) __builtin_amdgcn_readfirstlane(x)

__device__ __forceinline__ unsigned short f2bf(float f) {   // RNE f32->bf16
    union { float f; unsigned u; } v; v.f = f;
    unsigned r = v.u + 0x7FFFu + ((v.u >> 16) & 1u);
    return (unsigned short)(r >> 16);
}
__device__ __forceinline__ float bf2f(unsigned short h) {
    union { float f; unsigned u; } v; v.u = ((unsigned)h) << 16;
    return v.f;
}

// Dims: B=2, S=1024, C=512, H=8, hd=64, T=4.
// bits layout: [3(qkv)][4(t)][2(b)][8(h)][1024(s)] u64 (bit d = channel h*64+d)
// vt   layout: [2(b)][8(h)][4(t)][16(w)][64(d)]  u64
// ws usage: bits 1.5 MiB + vt 0.5 MiB = 2.0 MiB (unchanged).

// LDS byte offsets: 4 bf16 tiles [64 rows][64 k] = 8 KiB each, XOR-swizzled.
#define AH_OFF 0
#define AL_OFF 8192
#define BH_OFF 16384
#define BL_OFF 24576

// ---------------- MFMA GEMM (fused q|k|v) + LIF + ballot pack.
// C(2048x1536) = X(2048x512) @ Wcat^T via split-bf16: y ~= xh@wh + xh@wl + xl@wh
// (residual xl@wl ~ 5e-5; total y err ~1e-4 — safe, see journal flip analysis).
// Block: 64 rows x 64 ch (one matrix+head per n-tile), 4 waves (2x2 of 32x32).
// LDS tiles swizzled: byte = row*128 + ((slot16 ^ (row&7))<<4)  (G4 fix; the
// unswizzled 128B-row layout is a 16-way read conflict).
__global__ __launch_bounds__(256) void gemm_mfma_lif_pack(
    const float* __restrict__ x,
    const float* __restrict__ Wq,
    const float* __restrict__ Wk,
    const float* __restrict__ Wv,
    u64* __restrict__ bits)
{
    __shared__ __align__(16) char smem[32768];

    const int tid  = threadIdx.x;
    const int lane = tid & 63;
    const int wv   = RFL(tid >> 6);
    const int bx  = blockIdx.x;     // 32 row tiles of 64
    const int byn = blockIdx.y;     // 24 = 3 mat * 8 heads
    const int mat = byn >> 3, h = byn & 7;
    const float* W = (mat == 0) ? Wq : (mat == 1) ? Wk : Wv;

    const int srow = tid >> 2;      // staging: row 0..63
    const int q    = tid & 3;       // 16-float quarter of the 64-k slice
    const int r7   = srow & 7;

    const float* __restrict__ xsrc = x + ((size_t)(bx * 64 + srow)) * 512 + q * 16;
    const float* __restrict__ wsrc = W + ((size_t)(h * 64 + srow)) * 512 + q * 16;

    const int wm = wv >> 1, wn = wv & 1;
    const int lg = lane >> 4, lr = lane & 15;

    f32x4 acc[2][2] = {{{0.f,0.f,0.f,0.f},{0.f,0.f,0.f,0.f}},
                       {{0.f,0.f,0.f,0.f},{0.f,0.f,0.f,0.f}}};

    for (int k0 = 0; k0 < 512; k0 += 64) {
        // ---- stage A (x) and B (W) 64x64 f32 slices -> bf16 hi/lo, swizzled
#pragma unroll
        for (int ab = 0; ab < 2; ++ab) {
            const float* src = (ab == 0) ? (xsrc + k0) : (wsrc + k0);
            float va[16];
            const float4* s4 = (const float4*)src;
#pragma unroll
            for (int i = 0; i < 4; ++i) {
                const float4 t4 = s4[i];
                va[i*4+0] = t4.x; va[i*4+1] = t4.y; va[i*4+2] = t4.z; va[i*4+3] = t4.w;
            }
            unsigned short hs[16], ls[16];
#pragma unroll
            for (int i = 0; i < 16; ++i) {
                hs[i] = f2bf(va[i]);
                ls[i] = f2bf(va[i] - bf2f(hs[i]));
            }
            short8 vh0, vh1, vl0, vl1;
#pragma unroll
            for (int j = 0; j < 8; ++j) {
                vh0[j] = (short)hs[j];   vh1[j] = (short)hs[8+j];
                vl0[j] = (short)ls[j];   vl1[j] = (short)ls[8+j];
            }
            char* hb = smem + (ab ? BH_OFF : AH_OFF) + srow * 128;
            char* lb = smem + (ab ? BL_OFF : AL_OFF) + srow * 128;
            *(short8*)(hb + ((((q<<1)+0) ^ r7) << 4)) = vh0;
            *(short8*)(hb + ((((q<<1)+1) ^ r7) << 4)) = vh1;
            *(short8*)(lb + ((((q<<1)+0) ^ r7) << 4)) = vl0;
            *(short8*)(lb + ((((q<<1)+1) ^ r7) << 4)) = vl1;
        }
        __syncthreads();

        // ---- compute: 2 x (K=32) mfma steps, 3 split-bf16 passes each
#pragma unroll
        for (int kk = 0; kk < 64; kk += 32) {
            const int slotb = (kk >> 3) + lg;
            short8 ah[2], al[2], bh2[2], bl2[2];
#pragma unroll
            for (int fm = 0; fm < 2; ++fm) {
                const int row = wm * 32 + fm * 16 + lr;
                const int off = row * 128 + ((slotb ^ (row & 7)) << 4);
                ah[fm] = *(const short8*)(smem + AH_OFF + off);
                al[fm] = *(const short8*)(smem + AL_OFF + off);
            }
#pragma unroll
            for (int fn = 0; fn < 2; ++fn) {
                const int row = wn * 32 + fn * 16 + lr;
                const int off = row * 128 + ((slotb ^ (row & 7)) << 4);
                bh2[fn] = *(const short8*)(smem + BH_OFF + off);
                bl2[fn] = *(const short8*)(smem + BL_OFF + off);
            }
#pragma unroll
            for (int fm = 0; fm < 2; ++fm)
#pragma unroll
                for (int fn = 0; fn < 2; ++fn) {
                    acc[fm][fn] = __builtin_amdgcn_mfma_f32_16x16x32_bf16(
                        ah[fm], bh2[fn], acc[fm][fn], 0, 0, 0);
                    acc[fm][fn] = __builtin_amdgcn_mfma_f32_16x16x32_bf16(
                        ah[fm], bl2[fn], acc[fm][fn], 0, 0, 0);
                    acc[fm][fn] = __builtin_amdgcn_mfma_f32_16x16x32_bf16(
                        al[fm], bh2[fn], acc[fm][fn], 0, 0, 0);
                }
        }
        __syncthreads();
    }

    // ---- epilogue: y tile -> LDS (f32, pad 65), then LIF + ballot pack.
    float* yl = (float*)smem;
#pragma unroll
    for (int fm = 0; fm < 2; ++fm)
#pragma unroll
        for (int fn = 0; fn < 2; ++fn)
#pragma unroll
            for (int reg = 0; reg < 4; ++reg) {
                const int m_loc = wm * 32 + fm * 16 + lg * 4 + reg;  // C/D: row=(lane>>4)*4+reg
                const int n_loc = wn * 32 + fn * 16 + lr;            // col=lane&15
                yl[m_loc * 65 + n_loc] = acc[fm][fn][reg];
            }
    __syncthreads();

    for (int r = 0; r < 16; ++r) {
        const int lrow = wv * 16 + r;
        const float y = yl[lrow * 65 + lane];   // lane = channel d within head
        float v = 0.f;
        int sp[4];
#pragma unroll
        for (int t = 0; t < 4; ++t) {
            v = v + (y - v) * 0.5f;             // decay_input charge, tau=2
            const int s = (v - 1.0f >= 0.f) ? 1 : 0;
            v = s ? 0.f : v;                    // hard reset
            sp[t] = s;
        }
        const int grow = bx * 64 + lrow;
        const int bb = grow >> 10;
        const int ss = grow & 1023;
        u64* dst = bits + (((size_t)(mat * 4) * 2 + bb) * 8 + h) * 1024 + ss;
#pragma unroll
        for (int t = 0; t < 4; ++t) {
            const u64 msk = __ballot(sp[t]);
            if (lane == 0) dst[(size_t)t * (2 * 8 * 1024)] = msk;
        }
    }
}

// ---------------- Kernel T2: bit-transpose of v spikes (unchanged)
__global__ __launch_bounds__(256) void v_transpose2(
    const u64* __restrict__ bits,
    u64* __restrict__ vt)
{
    const int lane = threadIdx.x & 63;
    const int t  = threadIdx.x >> 6;
    const int b  = blockIdx.x;
    const int h  = blockIdx.y;
    const int wg = blockIdx.z;
    const u64* __restrict__ src = bits + (((size_t)(2 * 4 + t) * 2 + b) * 8 + h) * 1024;
    u64* __restrict__ dst = vt + (((size_t)b * 8 + h) * 4 + t) * 1024;
    for (int wi = 0; wi < 4; ++wi) {
        const int w = wg * 4 + wi;
        const u64 vword = src[(w << 6) + lane];
        u64 myword = 0;
#pragma unroll
        for (int d = 0; d < 64; ++d) {
            const u64 m = __ballot((int)((vword >> d) & 1ull));
            if (lane == d) myword = m;
        }
        dst[(w << 6) + lane] = myword;
    }
}

// ---------------- Kernel B3: exact q-row filter + integer LIF slow path (unchanged)
__global__ __launch_bounds__(256) void spike_attn3(
    const u64* __restrict__ bits,
    const u64* __restrict__ vt,
    float* __restrict__ out)
{
    const int lane = threadIdx.x & 63;
    const int wave = RFL((int)(threadIdx.x >> 6));
    const int rt = blockIdx.x;
    const int h  = blockIdx.y;
    const int b  = blockIdx.z;

    const int bh = b * 8 + h;
    const u64* __restrict__ qb  = bits + (size_t)bh * 1024;
    const u64* __restrict__ kb  = bits + (size_t)(64 + bh) * 1024;
    const u64* __restrict__ vtb = vt + (size_t)bh * 4096;

    int cs[4] = {0, 0, 0, 0};
    for (int w = 0; w < 16; ++w) {
#pragma unroll
        for (int t = 0; t < 4; ++t)
            cs[t] += (int)__popcll(vtb[t * 1024 + (w << 6) + lane]);
    }
    const float base = (float)(cs[0] + cs[1] + cs[2] + cs[3]) * (1.0f / 4096.0f);

    const float E1 = 0.36787944117144233f;
    const int s0 = rt * 32 + wave * 8;

    for (int r = 0; r < 8; ++r) {
        const int s = s0 + r;
        const u64 q0 = qb[s];
        const u64 q1 = qb[16384 + s];
        const u64 q2 = qb[32768 + s];
        const u64 q3 = qb[49152 + s];
        const int c0 = (int)__popcll(q0), c1 = (int)__popcll(q1);
        const int c2 = (int)__popcll(q2), c3 = (int)__popcll(q3);
        const int mx = max(max(c0, c1), max(c2, c3));

        float o = base;
        if (mx >= 9) {
            int msum[4] = {0, 0, 0, 0}, n11[4] = {0, 0, 0, 0};
            for (int w = 0; w < 16; ++w) {
                const int ko = (w << 6) + lane;
                const u64 kw0 = kb[ko];
                const u64 kw1 = kb[16384 + ko];
                const u64 kw2 = kb[32768 + ko];
                const u64 kw3 = kb[49152 + ko];
                const int pcs[4] = {
                    (int)__popcll(kw0 & q0), (int)__popcll(kw1 & q1),
                    (int)__popcll(kw2 & q2), (int)__popcll(kw3 & q3)};
                unsigned u = 0;
#pragma unroll
                for (int t = 0; t < 4; ++t) {
                    u = (u >> 1) + (unsigned)(pcs[t] << 2);
                    const int spk = (u >= 64u) ? 1 : 0;
                    const u64 msk = __ballot(spk);
                    u = spk ? 0u : u;
                    msum[t] += (int)__popcll(msk);
                    n11[t]  += (int)__popcll(msk & vtb[t * 1024 + ko]);
                }
            }
            o = 0.f;
#pragma unroll
            for (int t = 0; t < 4; ++t) {
                const float mf = (float)msum[t];
                const float Z  = mf + (1024.f - mf) * E1;
                const float p1 = 1.0f / Z;
                const float p0 = E1 / Z;
                o += p0 * (float)cs[t] + (p1 - p0) * (float)n11[t];
            }
            o *= 0.25f;
        }
        out[((size_t)b * 1024 + s) * 512 + (h << 6) + lane] = o;
    }
}

extern "C" void kernel_launch(void* const* d_in, const int* in_sizes, int n_in,
                              void* d_out, int out_size, void* d_ws, size_t ws_size,
                              hipStream_t stream) {
    const float* x  = (const float*)d_in[0];
    const float* Wq = (const float*)d_in[1];
    const float* Wk = (const float*)d_in[2];
    const float* Wv = (const float*)d_in[3];
    float* out = (float*)d_out;

    u64* bits = (u64*)d_ws;                          // 1.5 MiB
    u64* vt   = bits + (size_t)3 * 4 * 2 * 8 * 1024; // 0.5 MiB

    gemm_mfma_lif_pack<<<dim3(32, 24), 256, 0, stream>>>(x, Wq, Wk, Wv, bits);
    v_transpose2<<<dim3(2, 8, 4), 256, 0, stream>>>(bits, vt);
    spike_attn3<<<dim3(32, 8, 2), 256, 0, stream>>>(bits, vt, out);
}

// Round 6
// 51.466 us; speedup vs baseline: 3.8377x; 1.5124x over previous
//
#include <hip/hip_runtime.h>
#include <cstdint>

typedef unsigned long long u64;
typedef __attribute__((ext_vector_type(8))) short short8;   // 8 bf16 = 4 VGPR
typedef __attribute__((ext_vector_type(4))) float f32x4;

#define RFL(x) __builtin_amdgcn_readfirstlane(x)

__device__ __forceinline__ unsigned short f2bf(float f) {   // RNE f32->bf16
    union { float f; unsigned u; } v; v.f = f;
    unsigned r = v.u + 0x7FFFu + ((v.u >> 16) & 1u);
    return (unsigned short)(r >> 16);
}
__device__ __forceinline__ float bf2f(unsigned short h) {
    union { float f; unsigned u; } v; v.u = ((unsigned)h) << 16;
    return v.f;
}

// Dims: B=2, S=1024, C=512, H=8, hd=64, T=4.
// bits layout: [3(qkv)][4(t)][2(b)][8(h)][1024(s)] u64 (bit d = channel h*64+d)
// vt   layout: [2(b)][8(h)][4(t)][16(w)][64(d)]  u64
// ws usage: bits 1.5 MiB + vt 0.5 MiB = 2.0 MiB (unchanged).

#define AH_OFF 0
#define AL_OFF 8192
#define BH_OFF 16384
#define BL_OFF 24576

// ---------------- MFMA GEMM (fused q|k|v) + LIF + ballot pack (unchanged from R4).
__global__ __launch_bounds__(256) void gemm_mfma_lif_pack(
    const float* __restrict__ x,
    const float* __restrict__ Wq,
    const float* __restrict__ Wk,
    const float* __restrict__ Wv,
    u64* __restrict__ bits)
{
    __shared__ __align__(16) char smem[32768];

    const int tid  = threadIdx.x;
    const int lane = tid & 63;
    const int wv   = RFL(tid >> 6);
    const int bx  = blockIdx.x;     // 32 row tiles of 64
    const int byn = blockIdx.y;     // 24 = 3 mat * 8 heads
    const int mat = byn >> 3, h = byn & 7;
    const float* W = (mat == 0) ? Wq : (mat == 1) ? Wk : Wv;

    const int srow = tid >> 2;      // staging: row 0..63
    const int q    = tid & 3;       // 16-float quarter of the 64-k slice
    const int r7   = srow & 7;

    const float* __restrict__ xsrc = x + ((size_t)(bx * 64 + srow)) * 512 + q * 16;
    const float* __restrict__ wsrc = W + ((size_t)(h * 64 + srow)) * 512 + q * 16;

    const int wm = wv >> 1, wn = wv & 1;
    const int lg = lane >> 4, lr = lane & 15;

    f32x4 acc[2][2] = {{{0.f,0.f,0.f,0.f},{0.f,0.f,0.f,0.f}},
                       {{0.f,0.f,0.f,0.f},{0.f,0.f,0.f,0.f}}};

    for (int k0 = 0; k0 < 512; k0 += 64) {
#pragma unroll
        for (int ab = 0; ab < 2; ++ab) {
            const float* src = (ab == 0) ? (xsrc + k0) : (wsrc + k0);
            float va[16];
            const float4* s4 = (const float4*)src;
#pragma unroll
            for (int i = 0; i < 4; ++i) {
                const float4 t4 = s4[i];
                va[i*4+0] = t4.x; va[i*4+1] = t4.y; va[i*4+2] = t4.z; va[i*4+3] = t4.w;
            }
            unsigned short hs[16], ls[16];
#pragma unroll
            for (int i = 0; i < 16; ++i) {
                hs[i] = f2bf(va[i]);
                ls[i] = f2bf(va[i] - bf2f(hs[i]));
            }
            short8 vh0, vh1, vl0, vl1;
#pragma unroll
            for (int j = 0; j < 8; ++j) {
                vh0[j] = (short)hs[j];   vh1[j] = (short)hs[8+j];
                vl0[j] = (short)ls[j];   vl1[j] = (short)ls[8+j];
            }
            char* hb = smem + (ab ? BH_OFF : AH_OFF) + srow * 128;
            char* lb = smem + (ab ? BL_OFF : AL_OFF) + srow * 128;
            *(short8*)(hb + ((((q<<1)+0) ^ r7) << 4)) = vh0;
            *(short8*)(hb + ((((q<<1)+1) ^ r7) << 4)) = vh1;
            *(short8*)(lb + ((((q<<1)+0) ^ r7) << 4)) = vl0;
            *(short8*)(lb + ((((q<<1)+1) ^ r7) << 4)) = vl1;
        }
        __syncthreads();

#pragma unroll
        for (int kk = 0; kk < 64; kk += 32) {
            const int slotb = (kk >> 3) + lg;
            short8 ah[2], al[2], bh2[2], bl2[2];
#pragma unroll
            for (int fm = 0; fm < 2; ++fm) {
                const int row = wm * 32 + fm * 16 + lr;
                const int off = row * 128 + ((slotb ^ (row & 7)) << 4);
                ah[fm] = *(const short8*)(smem + AH_OFF + off);
                al[fm] = *(const short8*)(smem + AL_OFF + off);
            }
#pragma unroll
            for (int fn = 0; fn < 2; ++fn) {
                const int row = wn * 32 + fn * 16 + lr;
                const int off = row * 128 + ((slotb ^ (row & 7)) << 4);
                bh2[fn] = *(const short8*)(smem + BH_OFF + off);
                bl2[fn] = *(const short8*)(smem + BL_OFF + off);
            }
#pragma unroll
            for (int fm = 0; fm < 2; ++fm)
#pragma unroll
                for (int fn = 0; fn < 2; ++fn) {
                    acc[fm][fn] = __builtin_amdgcn_mfma_f32_16x16x32_bf16(
                        ah[fm], bh2[fn], acc[fm][fn], 0, 0, 0);
                    acc[fm][fn] = __builtin_amdgcn_mfma_f32_16x16x32_bf16(
                        ah[fm], bl2[fn], acc[fm][fn], 0, 0, 0);
                    acc[fm][fn] = __builtin_amdgcn_mfma_f32_16x16x32_bf16(
                        al[fm], bh2[fn], acc[fm][fn], 0, 0, 0);
                }
        }
        __syncthreads();
    }

    float* yl = (float*)smem;
#pragma unroll
    for (int fm = 0; fm < 2; ++fm)
#pragma unroll
        for (int fn = 0; fn < 2; ++fn)
#pragma unroll
            for (int reg = 0; reg < 4; ++reg) {
                const int m_loc = wm * 32 + fm * 16 + lg * 4 + reg;
                const int n_loc = wn * 32 + fn * 16 + lr;
                yl[m_loc * 65 + n_loc] = acc[fm][fn][reg];
            }
    __syncthreads();

    for (int r = 0; r < 16; ++r) {
        const int lrow = wv * 16 + r;
        const float y = yl[lrow * 65 + lane];
        float v = 0.f;
        int sp[4];
#pragma unroll
        for (int t = 0; t < 4; ++t) {
            v = v + (y - v) * 0.5f;
            const int s = (v - 1.0f >= 0.f) ? 1 : 0;
            v = s ? 0.f : v;
            sp[t] = s;
        }
        const int grow = bx * 64 + lrow;
        const int bb = grow >> 10;
        const int ss = grow & 1023;
        u64* dst = bits + (((size_t)(mat * 4) * 2 + bb) * 8 + h) * 1024 + ss;
#pragma unroll
        for (int t = 0; t < 4; ++t) {
            const u64 msk = __ballot(sp[t]);
            if (lane == 0) dst[(size_t)t * (2 * 8 * 1024)] = msk;
        }
    }
}

// ---------------- Kernel T2: bit-transpose of v spikes (unchanged)
__global__ __launch_bounds__(256) void v_transpose2(
    const u64* __restrict__ bits,
    u64* __restrict__ vt)
{
    const int lane = threadIdx.x & 63;
    const int t  = threadIdx.x >> 6;
    const int b  = blockIdx.x;
    const int h  = blockIdx.y;
    const int wg = blockIdx.z;
    const u64* __restrict__ src = bits + (((size_t)(2 * 4 + t) * 2 + b) * 8 + h) * 1024;
    u64* __restrict__ dst = vt + (((size_t)b * 8 + h) * 4 + t) * 1024;
    for (int wi = 0; wi < 4; ++wi) {
        const int w = wg * 4 + wi;
        const u64 vword = src[(w << 6) + lane];
        u64 myword = 0;
#pragma unroll
        for (int d = 0; d < 64; ++d) {
            const u64 m = __ballot((int)((vword >> d) & 1ull));
            if (lane == d) myword = m;
        }
        dst[(w << 6) + lane] = myword;
    }
}

// ---------------- Kernel B4: two-level conservative screen + exact slow path.
// Level 1 (per row, free): run the integer LIF recurrence on c_t=popcount(q_t)
//   (pc_t <= c_t, map monotone) -> B_t = (B_{t-1}>>1) + (c_t<<2); clean if all
//   B_t < 64. Exact upper bound including floors.
// Level 2 (cheap k-scan): spike requires max_t pc_t >= 9 (u <= 7.5*max pc);
//   one ballot per w, no LIF/msum/n11/vt work.
// Full exact integer-LIF path only if level 2 fires (~never on this data).
__global__ __launch_bounds__(256) void spike_attn4(
    const u64* __restrict__ bits,
    const u64* __restrict__ vt,
    float* __restrict__ out)
{
    const int lane = threadIdx.x & 63;
    const int wave = RFL((int)(threadIdx.x >> 6));
    const int rt = blockIdx.x;   // 64 tiles of 16 rows
    const int h  = blockIdx.y;
    const int b  = blockIdx.z;

    const int bh = b * 8 + h;
    const u64* __restrict__ qb  = bits + (size_t)bh * 1024;         // + t*16384 + s
    const u64* __restrict__ kb  = bits + (size_t)(64 + bh) * 1024;  // + t*16384 + k
    const u64* __restrict__ vtb = vt + (size_t)bh * 4096;           // + t*1024 + w*64 + d

    // column counts of v spikes (lane = d), per t
    int cs[4] = {0, 0, 0, 0};
    for (int w = 0; w < 16; ++w) {
#pragma unroll
        for (int t = 0; t < 4; ++t)
            cs[t] += (int)__popcll(vtb[t * 1024 + (w << 6) + lane]);
    }
    const float base = (float)(cs[0] + cs[1] + cs[2] + cs[3]) * (1.0f / 4096.0f);

    const float E1 = 0.36787944117144233f;  // expf(-1)
    const int s0 = rt * 16 + wave * 4;      // 4 rows per wave

#pragma unroll
    for (int r = 0; r < 4; ++r) {
        const int s = s0 + r;
        const u64 q0 = qb[s];
        const u64 q1 = qb[16384 + s];
        const u64 q2 = qb[32768 + s];
        const u64 q3 = qb[49152 + s];
        const int c0 = (int)__popcll(q0), c1 = (int)__popcll(q1);
        const int c2 = (int)__popcll(q2), c3 = (int)__popcll(q3);

        // level-1: LIF recurrence on c_t (upper bound on u_t, floors included)
        unsigned B = (unsigned)(c0 << 2);
        unsigned mB = B;
        B = (B >> 1) + (unsigned)(c1 << 2); mB = max(mB, B);
        B = (B >> 1) + (unsigned)(c2 << 2); mB = max(mB, B);
        B = (B >> 1) + (unsigned)(c3 << 2); mB = max(mB, B);

        float o = base;
        if (mB >= 64u) {            // wave-uniform; ~15-25% of rows
            // level-2: exact per-k screen, max_t pc_t >= 9 anywhere?
            u64 any = 0;
            for (int w = 0; w < 16; ++w) {
                const int ko = (w << 6) + lane;
                const int pc0 = (int)__popcll(kb[ko]          & q0);
                const int pc1 = (int)__popcll(kb[16384 + ko] & q1);
                const int pc2 = (int)__popcll(kb[32768 + ko] & q2);
                const int pc3 = (int)__popcll(kb[49152 + ko] & q3);
                const int mx = max(max(pc0, pc1), max(pc2, pc3));
                any |= __ballot(mx >= 9);
            }
            if (any) {              // wave-uniform; essentially never
                int msum[4] = {0, 0, 0, 0}, n11[4] = {0, 0, 0, 0};
                for (int w = 0; w < 16; ++w) {
                    const int ko = (w << 6) + lane;
                    const int pcs[4] = {
                        (int)__popcll(kb[ko]          & q0),
                        (int)__popcll(kb[16384 + ko] & q1),
                        (int)__popcll(kb[32768 + ko] & q2),
                        (int)__popcll(kb[49152 + ko] & q3)};
                    unsigned u = 0;
#pragma unroll
                    for (int t = 0; t < 4; ++t) {
                        u = (u >> 1) + (unsigned)(pcs[t] << 2);  // 64ths; exact
                        const int spk = (u >= 64u) ? 1 : 0;
                        const u64 msk = __ballot(spk);
                        u = spk ? 0u : u;
                        msum[t] += (int)__popcll(msk);
                        n11[t]  += (int)__popcll(msk & vtb[t * 1024 + ko]);
                    }
                }
                o = 0.f;
#pragma unroll
                for (int t = 0; t < 4; ++t) {
                    const float mf = (float)msum[t];
                    const float Z  = mf + (1024.f - mf) * E1;
                    const float p1 = 1.0f / Z;
                    const float p0 = E1 / Z;             // exactly 2^-10 when m==0
                    o += p0 * (float)cs[t] + (p1 - p0) * (float)n11[t];
                }
                o *= 0.25f;
            }
        }
        out[((size_t)b * 1024 + s) * 512 + (h << 6) + lane] = o;
    }
}

extern "C" void kernel_launch(void* const* d_in, const int* in_sizes, int n_in,
                              void* d_out, int out_size, void* d_ws, size_t ws_size,
                              hipStream_t stream) {
    const float* x  = (const float*)d_in[0];
    const float* Wq = (const float*)d_in[1];
    const float* Wk = (const float*)d_in[2];
    const float* Wv = (const float*)d_in[3];
    float* out = (float*)d_out;

    u64* bits = (u64*)d_ws;                          // 1.5 MiB
    u64* vt   = bits + (size_t)3 * 4 * 2 * 8 * 1024; // 0.5 MiB

    gemm_mfma_lif_pack<<<dim3(32, 24), 256, 0, stream>>>(x, Wq, Wk, Wv, bits);
    v_transpose2<<<dim3(2, 8, 4), 256, 0, stream>>>(bits, vt);
    spike_attn4<<<dim3(64, 8, 2), 256, 0, stream>>>(bits, vt, out);
}